// Round 17
// baseline (98.425 us; speedup 1.0000x reference)
//
#include <hip/hip_runtime.h>
#include <hip/hip_bf16.h>

#define NT 4096
#define DM 256
#define NH 8
#define HD 32
#define DFF 1024

typedef __attribute__((ext_vector_type(8))) short s8v;
typedef __attribute__((ext_vector_type(4))) float f4v;
typedef __attribute__((ext_vector_type(2))) float f2v;
typedef __attribute__((ext_vector_type(16))) float f16v;
typedef __attribute__((ext_vector_type(4))) int i4v;

static __device__ __forceinline__ unsigned short f2b(float f){
  union{float f; unsigned u;} v; v.f=f;
  return (unsigned short)((v.u + 0x7FFFu + ((v.u>>16)&1u))>>16);
}

// async global->LDS DMA, 16B per lane (emits global_load_lds_dwordx4).
static __device__ __forceinline__ void gl_lds16(const void* g, void* l){
  __builtin_amdgcn_global_load_lds(
      (const __attribute__((address_space(1))) unsigned int*)g,
      (__attribute__((address_space(3))) unsigned int*)l, 16, 0, 0);
}

// ---- prologue: prep_weights (blocks 0..127) | ln1 (128..255) ----
__global__ __launch_bounds__(256) void prologue_kernel(
    const float* __restrict__ wqkv, const float* __restrict__ wproj,
    const float* __restrict__ w1, const float* __restrict__ w2,
    unsigned short* __restrict__ wqkvT, unsigned short* __restrict__ wprojT,
    unsigned short* __restrict__ w1T, unsigned short* __restrict__ w2T,
    const float* __restrict__ x, const float* __restrict__ g1,
    const float* __restrict__ be1, unsigned short* __restrict__ h1){
  int bx = blockIdx.x;
  if (bx < 128){
    int t = bx*256 + threadIdx.x;
    const int stride = 128*256;
    for (int i=t;i<768*DM;i+=stride){int n=i>>8,k=i&255; wqkvT[i]=f2b(wqkv[k*768+n]);}
    for (int i=t;i<DM*DM;i+=stride){int n=i>>8,k=i&255; wprojT[i]=f2b(wproj[k*DM+n]);}
    for (int i=t;i<DFF*DM;i+=stride){int n=i>>8,k=i&255; w1T[i]=f2b(w1[k*DFF+n]);}
    for (int i=t;i<DM*DFF;i+=stride){int n=i/DFF,k=i-n*DFF; w2T[i]=f2b(w2[k*DM+n]);}
  } else {
    int wv = threadIdx.x>>6, lane = threadIdx.x&63;
    int rbase = (bx-128)*4 + wv;        // 512 row-streams, 8 rows each
    for (int j=0;j<8;j++){
      int row = rbase + j*512;
      float4 v = *(const float4*)(x + row*DM + lane*4);
      float s = v.x+v.y+v.z+v.w;
      float sq = v.x*v.x+v.y*v.y+v.z*v.z+v.w*v.w;
      #pragma unroll
      for (int m=1;m<64;m<<=1){ s += __shfl_xor(s,m); sq += __shfl_xor(sq,m); }
      float mu = s*(1.0f/DM);
      float rs = rsqrtf(sq*(1.0f/DM) - mu*mu + 1e-5f);
      float4 gv = *(const float4*)(g1 + lane*4);
      float4 bv = *(const float4*)(be1 + lane*4);
      ushort4 o;
      o.x = f2b((v.x-mu)*rs*gv.x + bv.x);
      o.y = f2b((v.y-mu)*rs*gv.y + bv.y);
      o.z = f2b((v.z-mu)*rs*gv.z + bv.z);
      o.w = f2b((v.w-mu)*rs*gv.w + bv.w);
      *(ushort4*)(h1 + row*DM + lane*4) = o;
    }
  }
}

// ---- qkv GEMM + pack_adj co-scheduled: grid (11,128) ----
template<int KD, int MODE>
__global__ __launch_bounds__(256,4) void gemm24(const unsigned short* __restrict__ A,
            const unsigned short* __restrict__ Wt,
            const int* __restrict__ adj, unsigned long long* __restrict__ mask,
            unsigned short* __restrict__ Qp, unsigned short* __restrict__ Kp,
            unsigned short* __restrict__ Vt){
  int wv = threadIdx.x>>6, lane = threadIdx.x&63;
  if (blockIdx.x >= 3){
    int bxl = (blockIdx.x-3)*128 + blockIdx.y;   // 0..1023
    int base = (bxl*4 + wv)*64;                  // 64 mask words per wave
    for (int it=0; it<16; ++it){
      int w0 = base + it*4;
      unsigned long long b0 = __ballot(adj[(long)(w0+0)*64 + lane]!=0);
      unsigned long long b1 = __ballot(adj[(long)(w0+1)*64 + lane]!=0);
      unsigned long long b2 = __ballot(adj[(long)(w0+2)*64 + lane]!=0);
      unsigned long long b3 = __ballot(adj[(long)(w0+3)*64 + lane]!=0);
      if (lane==0){ mask[w0]=b0; mask[w0+1]=b1; mask[w0+2]=b2; mask[w0+3]=b3; }
    }
    return;
  }
  int lo = lane&15, hi = lane>>4;
  int r0 = blockIdx.y*32;
  int cbase = blockIdx.x*256 + wv*16;
  const unsigned short* ar0 = A + (r0+lo)*KD + hi*8;
  const unsigned short* ar1 = ar0 + 16*KD;
  const unsigned short* br0 = Wt + (cbase     +lo)*KD + hi*8;
  const unsigned short* br1 = Wt + (cbase+ 64 +lo)*KD + hi*8;
  const unsigned short* br2 = Wt + (cbase+128 +lo)*KD + hi*8;
  const unsigned short* br3 = Wt + (cbase+192 +lo)*KD + hi*8;
  f4v c00={0,0,0,0},c01={0,0,0,0},c02={0,0,0,0},c03={0,0,0,0};
  f4v c10={0,0,0,0},c11={0,0,0,0},c12={0,0,0,0},c13={0,0,0,0};
  #pragma unroll 2
  for (int k0=0;k0<KD;k0+=32){
    s8v a0 = *(const s8v*)(ar0 + k0);
    s8v a1 = *(const s8v*)(ar1 + k0);
    s8v b0 = *(const s8v*)(br0 + k0);
    s8v b1 = *(const s8v*)(br1 + k0);
    s8v b2 = *(const s8v*)(br2 + k0);
    s8v b3 = *(const s8v*)(br3 + k0);
    c00 = __builtin_amdgcn_mfma_f32_16x16x32_bf16(a0,b0,c00,0,0,0);
    c10 = __builtin_amdgcn_mfma_f32_16x16x32_bf16(a1,b0,c10,0,0,0);
    c01 = __builtin_amdgcn_mfma_f32_16x16x32_bf16(a0,b1,c01,0,0,0);
    c11 = __builtin_amdgcn_mfma_f32_16x16x32_bf16(a1,b1,c11,0,0,0);
    c02 = __builtin_amdgcn_mfma_f32_16x16x32_bf16(a0,b2,c02,0,0,0);
    c12 = __builtin_amdgcn_mfma_f32_16x16x32_bf16(a1,b2,c12,0,0,0);
    c03 = __builtin_amdgcn_mfma_f32_16x16x32_bf16(a0,b3,c03,0,0,0);
    c13 = __builtin_amdgcn_mfma_f32_16x16x32_bf16(a1,b3,c13,0,0,0);
  }
  const float scl2 = (float)(0.17677669529663687 * 1.4426950408889634); // scl*log2e
  #pragma unroll
  for (int rt=0;rt<2;rt++){
    f4v e0 = rt? c10:c00, e1 = rt? c11:c01, e2 = rt? c12:c02, e3 = rt? c13:c03;
    int nb = r0 + rt*16 + hi*4;
    #pragma unroll
    for (int jj=0;jj<4;jj++){
      f4v acc = jj==0?e0 : jj==1?e1 : jj==2?e2 : e3;
      int c = cbase + jj*64 + lo;
      int which = c>>8, hd = c&255, hh = hd>>5, d = hd&31;
      #pragma unroll
      for (int r=0;r<4;r++){
        int n = nb + r;
        float val = acc[r];
        if (which==0) Qp[(hh*NT+n)*HD+d]=f2b(val*scl2);
        else if (which==1) Kp[(hh*NT+n)*HD+d]=f2b(val);
        else Vt[(hh*HD+d)*NT+n]=f2b(val);    // V stored transposed per head
      }
    }
  }
}

// ---- flash attention (r9 structure + 2-deep K prefetch) ----
// Theory: QK MFMA stalls on K-load latency -- K for tile t+1 was issued at
// t start (~250cy cover) vs L2 latency ~300-500cy under contention. Now K
// for t+2 issues at t start (kc/kn/km rotation, +16 VGPR -> ~96, same
// occupancy bucket 64<v<=128). V unchanged (consumed mid-tile, covered).
__global__ __launch_bounds__(512,2) void attn_kernel(
    const unsigned short* __restrict__ Q, const unsigned short* __restrict__ K,
    const unsigned short* __restrict__ Vt, const unsigned* __restrict__ mb32,
    unsigned short* __restrict__ out){
  __shared__ float Opart[8][32][34];
  __shared__ float llS[8][32];
  int wv = threadIdx.x>>6, lane = threadIdx.x&63;
  int l31 = lane&31, hi5 = lane>>5;
  int h = blockIdx.x, q0 = blockIdx.y*64;
  const unsigned short* QbA = Q + (h*NT + q0 + l31)*HD + hi5*8;
  const unsigned short* QbB = QbA + 32*HD;
  s8v bqA1 = *(const s8v*)(QbA);
  s8v bqA2 = *(const s8v*)(QbA + 16);
  s8v bqB1 = *(const s8v*)(QbB);
  s8v bqB2 = *(const s8v*)(QbB + 16);
  const unsigned short* Kb = K + h*NT*HD;
  const unsigned short* Vb = Vt + (h*HD + l31)*NT;
  const unsigned* mrowA = mb32 + (q0+l31)*(NT/32) + wv*16;
  const unsigned* mrowB = mrowA + 32*(NT/32);
  const float C0 = -11.541560327111707f;   // -8*log2e
  const f16v c0v = {C0,C0,C0,C0,C0,C0,C0,C0,C0,C0,C0,C0,C0,C0,C0,C0};
  f2v lacA = {0.f,0.f}, lacB = {0.f,0.f};
  f16v accA = {0,0,0,0,0,0,0,0,0,0,0,0,0,0,0,0};
  f16v accB = {0,0,0,0,0,0,0,0,0,0,0,0,0,0,0,0};
  union SU { f16v v; f2v p[8]; };
  const unsigned short* Kt0 = Kb + (wv*512 + l31)*HD + hi5*8;
  // K prefetch registers: kc = tile t, kn = t+1, km = t+2
  s8v kc1 = *(const s8v*)(Kt0);
  s8v kc2 = *(const s8v*)(Kt0 + 16);
  s8v kn1 = *(const s8v*)(Kt0 + 32*HD);
  s8v kn2 = *(const s8v*)(Kt0 + 32*HD + 16);
  for (int tg=0; tg<4; tg++){
    i4v mw4A = *(const i4v*)(mrowA + tg*4);
    i4v mw4B = *(const i4v*)(mrowB + tg*4);
    #pragma unroll
    for (int ti=0; ti<4; ti++){
      int t = tg*4 + ti;
      int m0 = wv*512 + t*32;
      // V for current tile: issue early so it lands before PV
      const unsigned short* Vtp = Vb + m0 + hi5*8;
      s8v av1 = *(const s8v*)(Vtp);
      s8v av2 = *(const s8v*)(Vtp + 16);
      // prefetch K tile t+2 (two tiles of compute cover its latency)
      int tm = (t<14)? t+2 : 15;
      const unsigned short* Ktm = Kb + (wv*512 + tm*32 + l31)*HD + hi5*8;
      s8v km1 = *(const s8v*)(Ktm);
      s8v km2 = *(const s8v*)(Ktm + 16);
      SU sa, sb;
      __builtin_amdgcn_s_setprio(1);
      sa.v = __builtin_amdgcn_mfma_f32_32x32x16_bf16(kc1, bqA1, c0v, 0,0,0);
      sa.v = __builtin_amdgcn_mfma_f32_32x32x16_bf16(kc2, bqA2, sa.v, 0,0,0);
      sb.v = __builtin_amdgcn_mfma_f32_32x32x16_bf16(kc1, bqB1, c0v, 0,0,0);
      sb.v = __builtin_amdgcn_mfma_f32_32x32x16_bf16(kc2, bqB2, sb.v, 0,0,0);
      __builtin_amdgcn_s_setprio(0);
      unsigned mwA = ((unsigned)mw4A[ti]) >> (4*hi5);
      unsigned mwB = ((unsigned)mw4B[ti]) >> (4*hi5);
      #pragma unroll
      for (int r=0;r<16;r++){
        int bp = (r&3)+8*(r>>2);
        float pa = __builtin_amdgcn_exp2f(sa.v[r]);
        float pb = __builtin_amdgcn_exp2f(sb.v[r]);
        sa.v[r] = ((mwA >> bp) & 1u) ? pa : 0.0f;
        sb.v[r] = ((mwB >> bp) & 1u) ? pb : 0.0f;
      }
      #pragma unroll
      for (int i=0;i<8;i++){ lacA += sa.p[i]; lacB += sb.p[i]; }
      unsigned a0,a1,a2,a3,a4,a5,a6,a7, b0,b1,b2,b3,b4,b5,b6,b7;
      asm("v_cvt_pk_bf16_f32 %0, %1, %2" : "=v"(a0) : "v"(sa.v[0]),  "v"(sa.v[1]));
      asm("v_cvt_pk_bf16_f32 %0, %1, %2" : "=v"(a1) : "v"(sa.v[2]),  "v"(sa.v[3]));
      asm("v_cvt_pk_bf16_f32 %0, %1, %2" : "=v"(a2) : "v"(sa.v[4]),  "v"(sa.v[5]));
      asm("v_cvt_pk_bf16_f32 %0, %1, %2" : "=v"(a3) : "v"(sa.v[6]),  "v"(sa.v[7]));
      asm("v_cvt_pk_bf16_f32 %0, %1, %2" : "=v"(a4) : "v"(sa.v[8]),  "v"(sa.v[9]));
      asm("v_cvt_pk_bf16_f32 %0, %1, %2" : "=v"(a5) : "v"(sa.v[10]), "v"(sa.v[11]));
      asm("v_cvt_pk_bf16_f32 %0, %1, %2" : "=v"(a6) : "v"(sa.v[12]), "v"(sa.v[13]));
      asm("v_cvt_pk_bf16_f32 %0, %1, %2" : "=v"(a7) : "v"(sa.v[14]), "v"(sa.v[15]));
      asm("v_permlane32_swap_b32 %0, %1" : "+v"(a0), "+v"(a2));
      asm("v_permlane32_swap_b32 %0, %1" : "+v"(a1), "+v"(a3));
      asm("v_permlane32_swap_b32 %0, %1" : "+v"(a4), "+v"(a6));
      asm("v_permlane32_swap_b32 %0, %1" : "+v"(a5), "+v"(a7));
      asm("v_cvt_pk_bf16_f32 %0, %1, %2" : "=v"(b0) : "v"(sb.v[0]),  "v"(sb.v[1]));
      asm("v_cvt_pk_bf16_f32 %0, %1, %2" : "=v"(b1) : "v"(sb.v[2]),  "v"(sb.v[3]));
      asm("v_cvt_pk_bf16_f32 %0, %1, %2" : "=v"(b2) : "v"(sb.v[4]),  "v"(sb.v[5]));
      asm("v_cvt_pk_bf16_f32 %0, %1, %2" : "=v"(b3) : "v"(sb.v[6]),  "v"(sb.v[7]));
      asm("v_cvt_pk_bf16_f32 %0, %1, %2" : "=v"(b4) : "v"(sb.v[8]),  "v"(sb.v[9]));
      asm("v_cvt_pk_bf16_f32 %0, %1, %2" : "=v"(b5) : "v"(sb.v[10]), "v"(sb.v[11]));
      asm("v_cvt_pk_bf16_f32 %0, %1, %2" : "=v"(b6) : "v"(sb.v[12]), "v"(sb.v[13]));
      asm("v_cvt_pk_bf16_f32 %0, %1, %2" : "=v"(b7) : "v"(sb.v[14]), "v"(sb.v[15]));
      asm("v_permlane32_swap_b32 %0, %1" : "+v"(b0), "+v"(b2));
      asm("v_permlane32_swap_b32 %0, %1" : "+v"(b1), "+v"(b3));
      asm("v_permlane32_swap_b32 %0, %1" : "+v"(b4), "+v"(b6));
      asm("v_permlane32_swap_b32 %0, %1" : "+v"(b5), "+v"(b7));
      i4v pA1i = {(int)a0,(int)a1,(int)a2,(int)a3};
      i4v pA2i = {(int)a4,(int)a5,(int)a6,(int)a7};
      i4v pB1i = {(int)b0,(int)b1,(int)b2,(int)b3};
      i4v pB2i = {(int)b4,(int)b5,(int)b6,(int)b7};
      s8v pA1 = __builtin_bit_cast(s8v, pA1i);
      s8v pA2 = __builtin_bit_cast(s8v, pA2i);
      s8v pB1 = __builtin_bit_cast(s8v, pB1i);
      s8v pB2 = __builtin_bit_cast(s8v, pB2i);
      __builtin_amdgcn_s_setprio(1);
      accA = __builtin_amdgcn_mfma_f32_32x32x16_bf16(av1, pA1, accA, 0,0,0);
      accA = __builtin_amdgcn_mfma_f32_32x32x16_bf16(av2, pA2, accA, 0,0,0);
      accB = __builtin_amdgcn_mfma_f32_32x32x16_bf16(av1, pB1, accB, 0,0,0);
      accB = __builtin_amdgcn_mfma_f32_32x32x16_bf16(av2, pB2, accB, 0,0,0);
      __builtin_amdgcn_s_setprio(0);
      kc1 = kn1; kc2 = kn2;         // rotate: t+1 becomes current
      kn1 = km1; kn2 = km2;         // t+2 becomes next
    }
  }
  int tid = threadIdx.x;
  int qq = tid>>4, dd = 2*(tid&15);
  // ---- pass A ----
  #pragma unroll
  for (int i=0;i<8;i++){
    int d = (2*i&3) + 8*(i>>1) + 4*hi5;
    float2 p2; p2.x = accA[2*i]; p2.y = accA[2*i+1];
    *(float2*)&Opart[wv][l31][d] = p2;
  }
  float lsumA = lacA[0] + lacA[1];
  lsumA += __shfl_xor(lsumA, 32);
  if (hi5==0) llS[wv][l31] = lsumA;
  __syncthreads();
  {
    float L=0.f, o0=0.f, o1=0.f;
    #pragma unroll
    for (int u=0;u<8;u++){
      L  += llS[u][qq];
      o0 += Opart[u][qq][dd];
      o1 += Opart[u][qq][dd+1];
    }
    float inv = 1.0f/L;
    float r0 = o0*inv, r1 = o1*inv;
    unsigned pw;
    asm("v_cvt_pk_bf16_f32 %0, %1, %2" : "=v"(pw) : "v"(r0), "v"(r1));
    *(unsigned*)(out + (q0+qq)*DM + h*HD + dd) = pw;
  }
  __syncthreads();
  // ---- pass B ----
  #pragma unroll
  for (int i=0;i<8;i++){
    int d = (2*i&3) + 8*(i>>1) + 4*hi5;
    float2 p2; p2.x = accB[2*i]; p2.y = accB[2*i+1];
    *(float2*)&Opart[wv][l31][d] = p2;
  }
  float lsumB = lacB[0] + lacB[1];
  lsumB += __shfl_xor(lsumB, 32);
  if (hi5==0) llS[wv][l31] = lsumB;
  __syncthreads();
  {
    float L=0.f, o0=0.f, o1=0.f;
    #pragma unroll
    for (int u=0;u<8;u++){
      L  += llS[u][qq];
      o0 += Opart[u][qq][dd];
      o1 += Opart[u][qq][dd+1];
    }
    float inv = 1.0f/L;
    float r0 = o0*inv, r1 = o1*inv;
    unsigned pw;
    asm("v_cvt_pk_bf16_f32 %0, %1, %2" : "=v"(pw) : "v"(r0), "v"(r1));
    *(unsigned*)(out + (q0+32+qq)*DM + h*HD + dd) = pw;
  }
}

// ---- fused tail (r16 verbatim: depth-3 counted-vmcnt staging pipeline) ----
__global__ __launch_bounds__(512,2) void tail_kernel(
    const unsigned short* __restrict__ ao, const unsigned short* __restrict__ wprojT,
    const float* __restrict__ bproj, const float* __restrict__ x,
    const float* __restrict__ g2, const float* __restrict__ be2,
    const unsigned short* __restrict__ w1T, const float* __restrict__ b1,
    const unsigned short* __restrict__ w2T, const float* __restrict__ b2,
    float* __restrict__ outp){
  __shared__ unsigned short h2L[16][DM];
  __shared__ unsigned short gL[16][DFF];
  __shared__ float Ss[8][16], Sq[8][16];
  __shared__ __align__(16) unsigned char wS[3][32768];
  int wv = threadIdx.x>>6, lane = threadIdx.x&63;
  int lo = lane&15, hi = lane>>4;
  int tid = threadIdx.x;
  int r0 = blockIdx.x*16;
  float t[2][4];                      // x2 residual, live across all phases

#define STAGE_W1(S_, BUF_)                                                    \
  do { int cb_ = (S_)>>2, kt_ = (S_)&3;                                       \
    _Pragma("unroll")                                                         \
    for (int rr=0; rr<4; ++rr){                                               \
      int col_ = cb_*256 + rr*64 + (tid>>3);                                  \
      int ko_  = (tid&7) ^ (col_&7);                                          \
      gl_lds16(w1T + col_*DM + kt_*64 + ko_*8,                                \
               &wS[BUF_][rr*8192 + tid*16]);                                  \
    } } while(0)

#define STAGE_W2(KT, BUF)                                                     \
  do { _Pragma("unroll")                                                      \
    for (int rr=0; rr<4; ++rr){                                               \
      int col_ = rr*64 + (tid>>3);                                            \
      int ko_  = (tid&7) ^ (col_&7);                                          \
      gl_lds16(w2T + col_*DFF + (KT)*64 + ko_*8,                              \
               &wS[BUF][rr*8192 + tid*16]);                                   \
    } } while(0)

#define STAGE_G(G_)                                                           \
  do { int gg_ = (G_);                                                        \
    if (gg_ < 16) { STAGE_W1(gg_, gg_%3); }                                   \
    else          { STAGE_W2(gg_-16, gg_%3); }                                \
  } while(0)

  // pre-issue tiles 0,1,2: they stream during the whole of phase 1.
  STAGE_G(0);
  STAGE_G(1);
  STAGE_G(2);

  // preload bias scalars so the pipelined loops contain NO VMEM
  // other than the staging DMAs (keeps vmcnt accounting exact).
  float b1r[4][2], b2r[2];
  #pragma unroll
  for (int cb=0; cb<4; ++cb){
    b1r[cb][0] = b1[cb*256 +        wv*16 + lo];
    b1r[cb][1] = b1[cb*256 + 128 +  wv*16 + lo];
  }
  b2r[0] = b2[       wv*16 + lo];
  b2r[1] = b2[128 +  wv*16 + lo];

  // ---- phase 1: proj GEMM (16 rows x 256 cols, K=256) + residual + LN ----
  {
    const unsigned short* ar  = ao + (r0+lo)*DM + hi*8;
    const unsigned short* pb0 = wprojT + (wv*16     +lo)*DM + hi*8;
    const unsigned short* pb1 = wprojT + (wv*16+128 +lo)*DM + hi*8;
    f4v a0={0,0,0,0}, a1={0,0,0,0};
    #pragma unroll
    for (int k0=0;k0<DM;k0+=32){
      s8v a = *(const s8v*)(ar + k0);
      a0 = __builtin_amdgcn_mfma_f32_16x16x32_bf16(a, *(const s8v*)(pb0+k0), a0,0,0,0);
      a1 = __builtin_amdgcn_mfma_f32_16x16x32_bf16(a, *(const s8v*)(pb1+k0), a1,0,0,0);
    }
    float sr[4]={0,0,0,0}, sq[4]={0,0,0,0};
    #pragma unroll
    for (int jj=0;jj<2;jj++){
      f4v acc = jj? a1 : a0;
      int c = jj*128 + wv*16 + lo;
      float bc = bproj[c];
      #pragma unroll
      for (int r=0;r<4;r++){
        int n = r0 + hi*4 + r;
        float tv = acc[r] + bc + x[n*DM+c];
        t[jj][r] = tv; sr[r] += tv; sq[r] += tv*tv;
      }
    }
    #pragma unroll
    for (int m=1;m<16;m<<=1){
      #pragma unroll
      for (int r=0;r<4;r++){ sr[r]+=__shfl_xor(sr[r],m); sq[r]+=__shfl_xor(sq[r],m); }
    }
    if (lo==0){
      #pragma unroll
      for (int r=0;r<4;r++){ Ss[wv][hi*4+r]=sr[r]; Sq[wv][hi*4+r]=sq[r]; }
    }
    __syncthreads();
    #pragma unroll
    for (int r=0;r<4;r++){
      int nl = hi*4+r;
      float S=0.f, Qs=0.f;
      #pragma unroll
      for (int u=0;u<8;u++){ S += Ss[u][nl]; Qs += Sq[u][nl]; }
      float mu = S*(1.0f/DM);
      float rs = rsqrtf(Qs*(1.0f/DM) - mu*mu + 1e-5f);
      #pragma unroll
      for (int jj=0;jj<2;jj++){
        int c = jj*128 + wv*16 + lo;
        unsigned short hv = f2b((t[jj][r]-mu)*rs*g2[c] + be2[c]);
        int g = c>>3;
        h2L[nl][((g^(nl&7))<<3) + (c&7)] = hv;
      }
    }
  }
  __syncthreads();   // h2L ready; tiles 0,1,2 landed (full vmcnt drain)

  // ---- phase 2: ff1 GEMM (16 x 1024, K=256) + gelu -> gL, pipelined ----
  for (int cb=0; cb<4; ++cb){
    f4v f0={0,0,0,0}, f1={0,0,0,0};
    int c0i = wv*16 + lo;
    int c1i = c0i + 128;
    #pragma unroll
    for (int kt=0; kt<4; ++kt){
      int g = cb*4 + kt;                       // global tile 0..15
      const unsigned char* bufp = wS[g%3];
      #pragma unroll
      for (int ks=0; ks<2; ++ks){
        int k0 = kt*64 + ks*32;
        s8v a  = *(const s8v*)&h2L[lo][(((hi + (k0>>3)) ^ (lo&7))<<3)];
        s8v bw0 = *(const s8v*)(bufp + c0i*128 + ((((ks*4)+hi) ^ (c0i&7))<<4));
        s8v bw1 = *(const s8v*)(bufp + c1i*128 + ((((ks*4)+hi) ^ (c1i&7))<<4));
        f0 = __builtin_amdgcn_mfma_f32_16x16x32_bf16(a, bw0, f0,0,0,0);
        f1 = __builtin_amdgcn_mfma_f32_16x16x32_bf16(a, bw1, f1,0,0,0);
      }
      asm volatile("" ::: "memory");
      __builtin_amdgcn_s_barrier();            // all waves done reading wS[g%3]
      STAGE_G(g+3);                            // g+3 <= 18 here
      if (g < 15){
        asm volatile("s_waitcnt vmcnt(8)" ::: "memory");  // tile g+1 landed
        __builtin_amdgcn_s_barrier();                     // ...for all waves
      }
    }
    // gelu epilogue for this col-block (no VMEM: bias preloaded)
    #pragma unroll
    for (int jj=0;jj<2;jj++){
      f4v acc = jj? f1 : f0;
      int c = cb*256 + jj*128 + wv*16 + lo;
      float bc = b1r[cb][jj];
      #pragma unroll
      for (int r=0;r<4;r++){
        int nl = hi*4+r;
        float xx = acc[r] + bc;
        float x2v = xx*xx;
        float arg = xx*(2.302340531f + 0.102952640f*x2v);
        float e  = __builtin_amdgcn_exp2f(arg);
        float rcp = __builtin_amdgcn_rcpf(e + 1.0f);
        unsigned short gv = f2b(xx - xx*rcp);
        int g = c>>3;
        gL[nl][((g^(nl&7))<<3) + (c&7)] = gv;
      }
    }
  }
  __syncthreads();   // gL ready; tiles 16,17,18 landed (full vmcnt drain)

  // ---- phase 3: ff2 GEMM (16 x 256, K=1024), pipelined w2 ----
  {
    f4v e0={0,0,0,0}, e1={0,0,0,0};
    int c0i = wv*16 + lo;
    int c1i = c0i + 128;
    for (int kt=0; kt<16; ++kt){
      int g = 16 + kt;                         // global tile 16..31
      const unsigned char* bufp = wS[g%3];
      #pragma unroll
      for (int ks=0; ks<2; ++ks){
        int k0 = kt*64 + ks*32;
        s8v a = *(const s8v*)&gL[lo][(((hi + (k0>>3)) ^ (lo&7))<<3)];
        s8v bw0 = *(const s8v*)(bufp + c0i*128 + ((((ks*4)+hi) ^ (c0i&7))<<4));
        s8v bw1 = *(const s8v*)(bufp + c1i*128 + ((((ks*4)+hi) ^ (c1i&7))<<4));
        e0 = __builtin_amdgcn_mfma_f32_16x16x32_bf16(a, bw0, e0,0,0,0);
        e1 = __builtin_amdgcn_mfma_f32_16x16x32_bf16(a, bw1, e1,0,0,0);
      }
      asm volatile("" ::: "memory");
      __builtin_amdgcn_s_barrier();            // all waves done reading wS[g%3]
      if (g+3 <= 31) { STAGE_G(g+3); }
      if (g <= 28){
        asm volatile("s_waitcnt vmcnt(8)" ::: "memory");  // tile g+1 landed
        __builtin_amdgcn_s_barrier();
      } else if (g == 29){
        asm volatile("s_waitcnt vmcnt(4)" ::: "memory");  // tile 30 landed
        __builtin_amdgcn_s_barrier();
      } else if (g == 30){
        asm volatile("s_waitcnt vmcnt(0)" ::: "memory");  // tile 31 landed
        __builtin_amdgcn_s_barrier();
      }
    }
    #pragma unroll
    for (int jj=0;jj<2;jj++){
      f4v acc = jj? e1 : e0;
      int c = jj*128 + wv*16 + lo;
      float bc = b2r[jj];
      #pragma unroll
      for (int r=0;r<4;r++){
        int n = r0 + hi*4 + r;
        outp[n*DM+c] = acc[r] + bc + t[jj][r];   // residual from registers
      }
    }
  }
#undef STAGE_G
#undef STAGE_W1
#undef STAGE_W2
}

extern "C" void kernel_launch(void* const* d_in, const int* in_sizes, int n_in,
                              void* d_out, int out_size, void* d_ws, size_t ws_size,
                              hipStream_t stream){
  const float* x     = (const float*)d_in[0];
  const int*   adj   = (const int*)d_in[1];
  const float* wqkv  = (const float*)d_in[2];
  const float* wproj = (const float*)d_in[3];
  const float* bproj = (const float*)d_in[4];
  const float* w1    = (const float*)d_in[5];
  const float* b1    = (const float*)d_in[6];
  const float* w2    = (const float*)d_in[7];
  const float* b2    = (const float*)d_in[8];
  const float* g1    = (const float*)d_in[9];
  const float* be1   = (const float*)d_in[10];
  const float* g2    = (const float*)d_in[11];
  const float* be2   = (const float*)d_in[12];

  char* ws = (char*)d_ws;
  unsigned short* h1    = (unsigned short*)(ws + (0u<<20));
  unsigned short* Qb    = (unsigned short*)(ws + (2u<<20));
  unsigned short* Kb    = (unsigned short*)(ws + (4u<<20));
  unsigned short* Vt    = (unsigned short*)(ws + (6u<<20));
  unsigned short* ao    = (unsigned short*)(ws + (8u<<20));
  unsigned short* wqkvT = (unsigned short*)(ws + (24u<<20));
  unsigned short* wprojT= (unsigned short*)(ws + (25u<<20));
  unsigned short* w1T   = (unsigned short*)(ws + (26u<<20));
  unsigned short* w2T   = (unsigned short*)(ws + (27u<<20));
  unsigned long long* mbits = (unsigned long long*)(ws + (28u<<20));
  float* outF = (float*)d_out;

  hipLaunchKernelGGL(prologue_kernel, dim3(256), dim3(256), 0, stream,
                     wqkv, wproj, w1, w2, wqkvT, wprojT, w1T, w2T,
                     x, g1, be1, h1);
  hipLaunchKernelGGL((gemm24<256,0>), dim3(11,128), dim3(256), 0, stream,
                     h1, wqkvT, adj, mbits, Qb, Kb, Vt);
  hipLaunchKernelGGL(attn_kernel, dim3(8,64), dim3(512), 0, stream,
                     Qb, Kb, Vt, (const unsigned*)mbits, ao);
  hipLaunchKernelGGL(tail_kernel, dim3(256), dim3(512), 0, stream,
                     ao, wprojT, bproj, x, g2, be2, w1T, b1, w2T, b2, outF);
}

// Round 18
// 98.251 us; speedup vs baseline: 1.0018x; 1.0018x over previous
//
#include <hip/hip_runtime.h>
#include <hip/hip_bf16.h>

#define NT 4096
#define DM 256
#define NH 8
#define HD 32
#define DFF 1024

typedef __attribute__((ext_vector_type(8))) short s8v;
typedef __attribute__((ext_vector_type(4))) float f4v;
typedef __attribute__((ext_vector_type(2))) float f2v;
typedef __attribute__((ext_vector_type(16))) float f16v;
typedef __attribute__((ext_vector_type(4))) int i4v;

static __device__ __forceinline__ unsigned short f2b(float f){
  union{float f; unsigned u;} v; v.f=f;
  return (unsigned short)((v.u + 0x7FFFu + ((v.u>>16)&1u))>>16);
}

// async global->LDS DMA, 16B per lane (emits global_load_lds_dwordx4).
static __device__ __forceinline__ void gl_lds16(const void* g, void* l){
  __builtin_amdgcn_global_load_lds(
      (const __attribute__((address_space(1))) unsigned int*)g,
      (__attribute__((address_space(3))) unsigned int*)l, 16, 0, 0);
}

// ---- prologue: prep_weights (blocks 0..127) | ln1 (128..255) ----
__global__ __launch_bounds__(256) void prologue_kernel(
    const float* __restrict__ wqkv, const float* __restrict__ wproj,
    const float* __restrict__ w1, const float* __restrict__ w2,
    unsigned short* __restrict__ wqkvT, unsigned short* __restrict__ wprojT,
    unsigned short* __restrict__ w1T, unsigned short* __restrict__ w2T,
    const float* __restrict__ x, const float* __restrict__ g1,
    const float* __restrict__ be1, unsigned short* __restrict__ h1){
  int bx = blockIdx.x;
  if (bx < 128){
    int t = bx*256 + threadIdx.x;
    const int stride = 128*256;
    for (int i=t;i<768*DM;i+=stride){int n=i>>8,k=i&255; wqkvT[i]=f2b(wqkv[k*768+n]);}
    for (int i=t;i<DM*DM;i+=stride){int n=i>>8,k=i&255; wprojT[i]=f2b(wproj[k*DM+n]);}
    for (int i=t;i<DFF*DM;i+=stride){int n=i>>8,k=i&255; w1T[i]=f2b(w1[k*DFF+n]);}
    for (int i=t;i<DM*DFF;i+=stride){int n=i/DFF,k=i-n*DFF; w2T[i]=f2b(w2[k*DM+n]);}
  } else {
    int wv = threadIdx.x>>6, lane = threadIdx.x&63;
    int rbase = (bx-128)*4 + wv;        // 512 row-streams, 8 rows each
    for (int j=0;j<8;j++){
      int row = rbase + j*512;
      float4 v = *(const float4*)(x + row*DM + lane*4);
      float s = v.x+v.y+v.z+v.w;
      float sq = v.x*v.x+v.y*v.y+v.z*v.z+v.w*v.w;
      #pragma unroll
      for (int m=1;m<64;m<<=1){ s += __shfl_xor(s,m); sq += __shfl_xor(sq,m); }
      float mu = s*(1.0f/DM);
      float rs = rsqrtf(sq*(1.0f/DM) - mu*mu + 1e-5f);
      float4 gv = *(const float4*)(g1 + lane*4);
      float4 bv = *(const float4*)(be1 + lane*4);
      ushort4 o;
      o.x = f2b((v.x-mu)*rs*gv.x + bv.x);
      o.y = f2b((v.y-mu)*rs*gv.y + bv.y);
      o.z = f2b((v.z-mu)*rs*gv.z + bv.z);
      o.w = f2b((v.w-mu)*rs*gv.w + bv.w);
      *(ushort4*)(h1 + row*DM + lane*4) = o;
    }
  }
}

// ---- qkv GEMM + pack_adj co-scheduled: grid (11,128) ----
template<int KD, int MODE>
__global__ __launch_bounds__(256,4) void gemm24(const unsigned short* __restrict__ A,
            const unsigned short* __restrict__ Wt,
            const int* __restrict__ adj, unsigned long long* __restrict__ mask,
            unsigned short* __restrict__ Qp, unsigned short* __restrict__ Kp,
            unsigned short* __restrict__ Vt){
  int wv = threadIdx.x>>6, lane = threadIdx.x&63;
  if (blockIdx.x >= 3){
    int bxl = (blockIdx.x-3)*128 + blockIdx.y;   // 0..1023
    int base = (bxl*4 + wv)*64;                  // 64 mask words per wave
    for (int it=0; it<16; ++it){
      int w0 = base + it*4;
      unsigned long long b0 = __ballot(adj[(long)(w0+0)*64 + lane]!=0);
      unsigned long long b1 = __ballot(adj[(long)(w0+1)*64 + lane]!=0);
      unsigned long long b2 = __ballot(adj[(long)(w0+2)*64 + lane]!=0);
      unsigned long long b3 = __ballot(adj[(long)(w0+3)*64 + lane]!=0);
      if (lane==0){ mask[w0]=b0; mask[w0+1]=b1; mask[w0+2]=b2; mask[w0+3]=b3; }
    }
    return;
  }
  int lo = lane&15, hi = lane>>4;
  int r0 = blockIdx.y*32;
  int cbase = blockIdx.x*256 + wv*16;
  const unsigned short* ar0 = A + (r0+lo)*KD + hi*8;
  const unsigned short* ar1 = ar0 + 16*KD;
  const unsigned short* br0 = Wt + (cbase     +lo)*KD + hi*8;
  const unsigned short* br1 = Wt + (cbase+ 64 +lo)*KD + hi*8;
  const unsigned short* br2 = Wt + (cbase+128 +lo)*KD + hi*8;
  const unsigned short* br3 = Wt + (cbase+192 +lo)*KD + hi*8;
  f4v c00={0,0,0,0},c01={0,0,0,0},c02={0,0,0,0},c03={0,0,0,0};
  f4v c10={0,0,0,0},c11={0,0,0,0},c12={0,0,0,0},c13={0,0,0,0};
  #pragma unroll 2
  for (int k0=0;k0<KD;k0+=32){
    s8v a0 = *(const s8v*)(ar0 + k0);
    s8v a1 = *(const s8v*)(ar1 + k0);
    s8v b0 = *(const s8v*)(br0 + k0);
    s8v b1 = *(const s8v*)(br1 + k0);
    s8v b2 = *(const s8v*)(br2 + k0);
    s8v b3 = *(const s8v*)(br3 + k0);
    c00 = __builtin_amdgcn_mfma_f32_16x16x32_bf16(a0,b0,c00,0,0,0);
    c10 = __builtin_amdgcn_mfma_f32_16x16x32_bf16(a1,b0,c10,0,0,0);
    c01 = __builtin_amdgcn_mfma_f32_16x16x32_bf16(a0,b1,c01,0,0,0);
    c11 = __builtin_amdgcn_mfma_f32_16x16x32_bf16(a1,b1,c11,0,0,0);
    c02 = __builtin_amdgcn_mfma_f32_16x16x32_bf16(a0,b2,c02,0,0,0);
    c12 = __builtin_amdgcn_mfma_f32_16x16x32_bf16(a1,b2,c12,0,0,0);
    c03 = __builtin_amdgcn_mfma_f32_16x16x32_bf16(a0,b3,c03,0,0,0);
    c13 = __builtin_amdgcn_mfma_f32_16x16x32_bf16(a1,b3,c13,0,0,0);
  }
  const float scl2 = (float)(0.17677669529663687 * 1.4426950408889634); // scl*log2e
  #pragma unroll
  for (int rt=0;rt<2;rt++){
    f4v e0 = rt? c10:c00, e1 = rt? c11:c01, e2 = rt? c12:c02, e3 = rt? c13:c03;
    int nb = r0 + rt*16 + hi*4;
    #pragma unroll
    for (int jj=0;jj<4;jj++){
      f4v acc = jj==0?e0 : jj==1?e1 : jj==2?e2 : e3;
      int c = cbase + jj*64 + lo;
      int which = c>>8, hd = c&255, hh = hd>>5, d = hd&31;
      #pragma unroll
      for (int r=0;r<4;r++){
        int n = nb + r;
        float val = acc[r];
        if (which==0) Qp[(hh*NT+n)*HD+d]=f2b(val*scl2);
        else if (which==1) Kp[(hh*NT+n)*HD+d]=f2b(val);
        else Vt[(hh*HD+d)*NT+n]=f2b(val);    // V stored transposed per head
      }
    }
  }
}

// ---- flash attention (r9 structure, frozen; ~49us) ----
__global__ __launch_bounds__(512,2) void attn_kernel(
    const unsigned short* __restrict__ Q, const unsigned short* __restrict__ K,
    const unsigned short* __restrict__ Vt, const unsigned* __restrict__ mb32,
    unsigned short* __restrict__ out){
  __shared__ float Opart[8][32][34];
  __shared__ float llS[8][32];
  int wv = threadIdx.x>>6, lane = threadIdx.x&63;
  int l31 = lane&31, hi5 = lane>>5;
  int h = blockIdx.x, q0 = blockIdx.y*64;
  const unsigned short* QbA = Q + (h*NT + q0 + l31)*HD + hi5*8;
  const unsigned short* QbB = QbA + 32*HD;
  s8v bqA1 = *(const s8v*)(QbA);
  s8v bqA2 = *(const s8v*)(QbA + 16);
  s8v bqB1 = *(const s8v*)(QbB);
  s8v bqB2 = *(const s8v*)(QbB + 16);
  const unsigned short* Kb = K + h*NT*HD;
  const unsigned short* Vb = Vt + (h*HD + l31)*NT;
  const unsigned* mrowA = mb32 + (q0+l31)*(NT/32) + wv*16;
  const unsigned* mrowB = mrowA + 32*(NT/32);
  const float C0 = -11.541560327111707f;   // -8*log2e
  const f16v c0v = {C0,C0,C0,C0,C0,C0,C0,C0,C0,C0,C0,C0,C0,C0,C0,C0};
  f2v lacA = {0.f,0.f}, lacB = {0.f,0.f};
  f16v accA = {0,0,0,0,0,0,0,0,0,0,0,0,0,0,0,0};
  f16v accB = {0,0,0,0,0,0,0,0,0,0,0,0,0,0,0,0};
  union SU { f16v v; f2v p[8]; };
  const unsigned short* Kt0 = Kb + (wv*512 + l31)*HD + hi5*8;
  s8v kc1 = *(const s8v*)(Kt0);
  s8v kc2 = *(const s8v*)(Kt0 + 16);
  for (int tg=0; tg<4; tg++){
    i4v mw4A = *(const i4v*)(mrowA + tg*4);
    i4v mw4B = *(const i4v*)(mrowB + tg*4);
    #pragma unroll
    for (int ti=0; ti<4; ti++){
      int t = tg*4 + ti;
      int m0 = wv*512 + t*32;
      const unsigned short* Vtp = Vb + m0 + hi5*8;
      s8v av1 = *(const s8v*)(Vtp);
      s8v av2 = *(const s8v*)(Vtp + 16);
      int tn = (t<15)? t+1 : 15;
      const unsigned short* Ktn = Kb + (wv*512 + tn*32 + l31)*HD + hi5*8;
      s8v kn1 = *(const s8v*)(Ktn);
      s8v kn2 = *(const s8v*)(Ktn + 16);
      SU sa, sb;
      __builtin_amdgcn_s_setprio(1);
      sa.v = __builtin_amdgcn_mfma_f32_32x32x16_bf16(kc1, bqA1, c0v, 0,0,0);
      sa.v = __builtin_amdgcn_mfma_f32_32x32x16_bf16(kc2, bqA2, sa.v, 0,0,0);
      sb.v = __builtin_amdgcn_mfma_f32_32x32x16_bf16(kc1, bqB1, c0v, 0,0,0);
      sb.v = __builtin_amdgcn_mfma_f32_32x32x16_bf16(kc2, bqB2, sb.v, 0,0,0);
      __builtin_amdgcn_s_setprio(0);
      unsigned mwA = ((unsigned)mw4A[ti]) >> (4*hi5);
      unsigned mwB = ((unsigned)mw4B[ti]) >> (4*hi5);
      #pragma unroll
      for (int r=0;r<16;r++){
        int bp = (r&3)+8*(r>>2);
        float pa = __builtin_amdgcn_exp2f(sa.v[r]);
        float pb = __builtin_amdgcn_exp2f(sb.v[r]);
        sa.v[r] = ((mwA >> bp) & 1u) ? pa : 0.0f;
        sb.v[r] = ((mwB >> bp) & 1u) ? pb : 0.0f;
      }
      #pragma unroll
      for (int i=0;i<8;i++){ lacA += sa.p[i]; lacB += sb.p[i]; }
      unsigned a0,a1,a2,a3,a4,a5,a6,a7, b0,b1,b2,b3,b4,b5,b6,b7;
      asm("v_cvt_pk_bf16_f32 %0, %1, %2" : "=v"(a0) : "v"(sa.v[0]),  "v"(sa.v[1]));
      asm("v_cvt_pk_bf16_f32 %0, %1, %2" : "=v"(a1) : "v"(sa.v[2]),  "v"(sa.v[3]));
      asm("v_cvt_pk_bf16_f32 %0, %1, %2" : "=v"(a2) : "v"(sa.v[4]),  "v"(sa.v[5]));
      asm("v_cvt_pk_bf16_f32 %0, %1, %2" : "=v"(a3) : "v"(sa.v[6]),  "v"(sa.v[7]));
      asm("v_cvt_pk_bf16_f32 %0, %1, %2" : "=v"(a4) : "v"(sa.v[8]),  "v"(sa.v[9]));
      asm("v_cvt_pk_bf16_f32 %0, %1, %2" : "=v"(a5) : "v"(sa.v[10]), "v"(sa.v[11]));
      asm("v_cvt_pk_bf16_f32 %0, %1, %2" : "=v"(a6) : "v"(sa.v[12]), "v"(sa.v[13]));
      asm("v_cvt_pk_bf16_f32 %0, %1, %2" : "=v"(a7) : "v"(sa.v[14]), "v"(sa.v[15]));
      asm("v_permlane32_swap_b32 %0, %1" : "+v"(a0), "+v"(a2));
      asm("v_permlane32_swap_b32 %0, %1" : "+v"(a1), "+v"(a3));
      asm("v_permlane32_swap_b32 %0, %1" : "+v"(a4), "+v"(a6));
      asm("v_permlane32_swap_b32 %0, %1" : "+v"(a5), "+v"(a7));
      asm("v_cvt_pk_bf16_f32 %0, %1, %2" : "=v"(b0) : "v"(sb.v[0]),  "v"(sb.v[1]));
      asm("v_cvt_pk_bf16_f32 %0, %1, %2" : "=v"(b1) : "v"(sb.v[2]),  "v"(sb.v[3]));
      asm("v_cvt_pk_bf16_f32 %0, %1, %2" : "=v"(b2) : "v"(sb.v[4]),  "v"(sb.v[5]));
      asm("v_cvt_pk_bf16_f32 %0, %1, %2" : "=v"(b3) : "v"(sb.v[6]),  "v"(sb.v[7]));
      asm("v_cvt_pk_bf16_f32 %0, %1, %2" : "=v"(b4) : "v"(sb.v[8]),  "v"(sb.v[9]));
      asm("v_cvt_pk_bf16_f32 %0, %1, %2" : "=v"(b5) : "v"(sb.v[10]), "v"(sb.v[11]));
      asm("v_cvt_pk_bf16_f32 %0, %1, %2" : "=v"(b6) : "v"(sb.v[12]), "v"(sb.v[13]));
      asm("v_cvt_pk_bf16_f32 %0, %1, %2" : "=v"(b7) : "v"(sb.v[14]), "v"(sb.v[15]));
      asm("v_permlane32_swap_b32 %0, %1" : "+v"(b0), "+v"(b2));
      asm("v_permlane32_swap_b32 %0, %1" : "+v"(b1), "+v"(b3));
      asm("v_permlane32_swap_b32 %0, %1" : "+v"(b4), "+v"(b6));
      asm("v_permlane32_swap_b32 %0, %1" : "+v"(b5), "+v"(b7));
      i4v pA1i = {(int)a0,(int)a1,(int)a2,(int)a3};
      i4v pA2i = {(int)a4,(int)a5,(int)a6,(int)a7};
      i4v pB1i = {(int)b0,(int)b1,(int)b2,(int)b3};
      i4v pB2i = {(int)b4,(int)b5,(int)b6,(int)b7};
      s8v pA1 = __builtin_bit_cast(s8v, pA1i);
      s8v pA2 = __builtin_bit_cast(s8v, pA2i);
      s8v pB1 = __builtin_bit_cast(s8v, pB1i);
      s8v pB2 = __builtin_bit_cast(s8v, pB2i);
      __builtin_amdgcn_s_setprio(1);
      accA = __builtin_amdgcn_mfma_f32_32x32x16_bf16(av1, pA1, accA, 0,0,0);
      accA = __builtin_amdgcn_mfma_f32_32x32x16_bf16(av2, pA2, accA, 0,0,0);
      accB = __builtin_amdgcn_mfma_f32_32x32x16_bf16(av1, pB1, accB, 0,0,0);
      accB = __builtin_amdgcn_mfma_f32_32x32x16_bf16(av2, pB2, accB, 0,0,0);
      __builtin_amdgcn_s_setprio(0);
      kc1 = kn1; kc2 = kn2;
    }
  }
  int tid = threadIdx.x;
  int qq = tid>>4, dd = 2*(tid&15);
  // ---- pass A ----
  #pragma unroll
  for (int i=0;i<8;i++){
    int d = (2*i&3) + 8*(i>>1) + 4*hi5;
    float2 p2; p2.x = accA[2*i]; p2.y = accA[2*i+1];
    *(float2*)&Opart[wv][l31][d] = p2;
  }
  float lsumA = lacA[0] + lacA[1];
  lsumA += __shfl_xor(lsumA, 32);
  if (hi5==0) llS[wv][l31] = lsumA;
  __syncthreads();
  {
    float L=0.f, o0=0.f, o1=0.f;
    #pragma unroll
    for (int u=0;u<8;u++){
      L  += llS[u][qq];
      o0 += Opart[u][qq][dd];
      o1 += Opart[u][qq][dd+1];
    }
    float inv = 1.0f/L;
    float r0 = o0*inv, r1 = o1*inv;
    unsigned pw;
    asm("v_cvt_pk_bf16_f32 %0, %1, %2" : "=v"(pw) : "v"(r0), "v"(r1));
    *(unsigned*)(out + (q0+qq)*DM + h*HD + dd) = pw;
  }
  __syncthreads();
  // ---- pass B ----
  #pragma unroll
  for (int i=0;i<8;i++){
    int d = (2*i&3) + 8*(i>>1) + 4*hi5;
    float2 p2; p2.x = accB[2*i]; p2.y = accB[2*i+1];
    *(float2*)&Opart[wv][l31][d] = p2;
  }
  float lsumB = lacB[0] + lacB[1];
  lsumB += __shfl_xor(lsumB, 32);
  if (hi5==0) llS[wv][l31] = lsumB;
  __syncthreads();
  {
    float L=0.f, o0=0.f, o1=0.f;
    #pragma unroll
    for (int u=0;u<8;u++){
      L  += llS[u][qq];
      o0 += Opart[u][qq][dd];
      o1 += Opart[u][qq][dd+1];
    }
    float inv = 1.0f/L;
    float r0 = o0*inv, r1 = o1*inv;
    unsigned pw;
    asm("v_cvt_pk_bf16_f32 %0, %1, %2" : "=v"(pw) : "v"(r0), "v"(r1));
    *(unsigned*)(out + (q0+32+qq)*DM + h*HD + dd) = pw;
  }
}

// ---- fused tail (depth-3 counted-vmcnt staging pipeline; best measured) ----
__global__ __launch_bounds__(512,2) void tail_kernel(
    const unsigned short* __restrict__ ao, const unsigned short* __restrict__ wprojT,
    const float* __restrict__ bproj, const float* __restrict__ x,
    const float* __restrict__ g2, const float* __restrict__ be2,
    const unsigned short* __restrict__ w1T, const float* __restrict__ b1,
    const unsigned short* __restrict__ w2T, const float* __restrict__ b2,
    float* __restrict__ outp){
  __shared__ unsigned short h2L[16][DM];
  __shared__ unsigned short gL[16][DFF];
  __shared__ float Ss[8][16], Sq[8][16];
  __shared__ __align__(16) unsigned char wS[3][32768];
  int wv = threadIdx.x>>6, lane = threadIdx.x&63;
  int lo = lane&15, hi = lane>>4;
  int tid = threadIdx.x;
  int r0 = blockIdx.x*16;
  float t[2][4];                      // x2 residual, live across all phases

#define STAGE_W1(S_, BUF_)                                                    \
  do { int cb_ = (S_)>>2, kt_ = (S_)&3;                                       \
    _Pragma("unroll")                                                         \
    for (int rr=0; rr<4; ++rr){                                               \
      int col_ = cb_*256 + rr*64 + (tid>>3);                                  \
      int ko_  = (tid&7) ^ (col_&7);                                          \
      gl_lds16(w1T + col_*DM + kt_*64 + ko_*8,                                \
               &wS[BUF_][rr*8192 + tid*16]);                                  \
    } } while(0)

#define STAGE_W2(KT, BUF)                                                     \
  do { _Pragma("unroll")                                                      \
    for (int rr=0; rr<4; ++rr){                                               \
      int col_ = rr*64 + (tid>>3);                                            \
      int ko_  = (tid&7) ^ (col_&7);                                          \
      gl_lds16(w2T + col_*DFF + (KT)*64 + ko_*8,                              \
               &wS[BUF][rr*8192 + tid*16]);                                   \
    } } while(0)

#define STAGE_G(G_)                                                           \
  do { int gg_ = (G_);                                                        \
    if (gg_ < 16) { STAGE_W1(gg_, gg_%3); }                                   \
    else          { STAGE_W2(gg_-16, gg_%3); }                                \
  } while(0)

  // pre-issue tiles 0,1,2: they stream during the whole of phase 1.
  STAGE_G(0);
  STAGE_G(1);
  STAGE_G(2);

  // preload bias scalars so the pipelined loops contain NO VMEM
  // other than the staging DMAs (keeps vmcnt accounting exact).
  float b1r[4][2], b2r[2];
  #pragma unroll
  for (int cb=0; cb<4; ++cb){
    b1r[cb][0] = b1[cb*256 +        wv*16 + lo];
    b1r[cb][1] = b1[cb*256 + 128 +  wv*16 + lo];
  }
  b2r[0] = b2[       wv*16 + lo];
  b2r[1] = b2[128 +  wv*16 + lo];

  // ---- phase 1: proj GEMM (16 rows x 256 cols, K=256) + residual + LN ----
  {
    const unsigned short* ar  = ao + (r0+lo)*DM + hi*8;
    const unsigned short* pb0 = wprojT + (wv*16     +lo)*DM + hi*8;
    const unsigned short* pb1 = wprojT + (wv*16+128 +lo)*DM + hi*8;
    f4v a0={0,0,0,0}, a1={0,0,0,0};
    #pragma unroll
    for (int k0=0;k0<DM;k0+=32){
      s8v a = *(const s8v*)(ar + k0);
      a0 = __builtin_amdgcn_mfma_f32_16x16x32_bf16(a, *(const s8v*)(pb0+k0), a0,0,0,0);
      a1 = __builtin_amdgcn_mfma_f32_16x16x32_bf16(a, *(const s8v*)(pb1+k0), a1,0,0,0);
    }
    float sr[4]={0,0,0,0}, sq[4]={0,0,0,0};
    #pragma unroll
    for (int jj=0;jj<2;jj++){
      f4v acc = jj? a1 : a0;
      int c = jj*128 + wv*16 + lo;
      float bc = bproj[c];
      #pragma unroll
      for (int r=0;r<4;r++){
        int n = r0 + hi*4 + r;
        float tv = acc[r] + bc + x[n*DM+c];
        t[jj][r] = tv; sr[r] += tv; sq[r] += tv*tv;
      }
    }
    #pragma unroll
    for (int m=1;m<16;m<<=1){
      #pragma unroll
      for (int r=0;r<4;r++){ sr[r]+=__shfl_xor(sr[r],m); sq[r]+=__shfl_xor(sq[r],m); }
    }
    if (lo==0){
      #pragma unroll
      for (int r=0;r<4;r++){ Ss[wv][hi*4+r]=sr[r]; Sq[wv][hi*4+r]=sq[r]; }
    }
    __syncthreads();
    #pragma unroll
    for (int r=0;r<4;r++){
      int nl = hi*4+r;
      float S=0.f, Qs=0.f;
      #pragma unroll
      for (int u=0;u<8;u++){ S += Ss[u][nl]; Qs += Sq[u][nl]; }
      float mu = S*(1.0f/DM);
      float rs = rsqrtf(Qs*(1.0f/DM) - mu*mu + 1e-5f);
      #pragma unroll
      for (int jj=0;jj<2;jj++){
        int c = jj*128 + wv*16 + lo;
        unsigned short hv = f2b((t[jj][r]-mu)*rs*g2[c] + be2[c]);
        int g = c>>3;
        h2L[nl][((g^(nl&7))<<3) + (c&7)] = hv;
      }
    }
  }
  __syncthreads();   // h2L ready; tiles 0,1,2 landed (full vmcnt drain)

  // ---- phase 2: ff1 GEMM (16 x 1024, K=256) + gelu -> gL, pipelined ----
  for (int cb=0; cb<4; ++cb){
    f4v f0={0,0,0,0}, f1={0,0,0,0};
    int c0i = wv*16 + lo;
    int c1i = c0i + 128;
    #pragma unroll
    for (int kt=0; kt<4; ++kt){
      int g = cb*4 + kt;                       // global tile 0..15
      const unsigned char* bufp = wS[g%3];
      #pragma unroll
      for (int ks=0; ks<2; ++ks){
        int k0 = kt*64 + ks*32;
        s8v a  = *(const s8v*)&h2L[lo][(((hi + (k0>>3)) ^ (lo&7))<<3)];
        s8v bw0 = *(const s8v*)(bufp + c0i*128 + ((((ks*4)+hi) ^ (c0i&7))<<4));
        s8v bw1 = *(const s8v*)(bufp + c1i*128 + ((((ks*4)+hi) ^ (c1i&7))<<4));
        f0 = __builtin_amdgcn_mfma_f32_16x16x32_bf16(a, bw0, f0,0,0,0);
        f1 = __builtin_amdgcn_mfma_f32_16x16x32_bf16(a, bw1, f1,0,0,0);
      }
      asm volatile("" ::: "memory");
      __builtin_amdgcn_s_barrier();            // all waves done reading wS[g%3]
      STAGE_G(g+3);                            // g+3 <= 18 here
      if (g < 15){
        asm volatile("s_waitcnt vmcnt(8)" ::: "memory");  // tile g+1 landed
        __builtin_amdgcn_s_barrier();                     // ...for all waves
      }
    }
    // gelu epilogue for this col-block (no VMEM: bias preloaded)
    #pragma unroll
    for (int jj=0;jj<2;jj++){
      f4v acc = jj? f1 : f0;
      int c = cb*256 + jj*128 + wv*16 + lo;
      float bc = b1r[cb][jj];
      #pragma unroll
      for (int r=0;r<4;r++){
        int nl = hi*4+r;
        float xx = acc[r] + bc;
        float x2v = xx*xx;
        float arg = xx*(2.302340531f + 0.102952640f*x2v);
        float e  = __builtin_amdgcn_exp2f(arg);
        float rcp = __builtin_amdgcn_rcpf(e + 1.0f);
        unsigned short gv = f2b(xx - xx*rcp);
        int g = c>>3;
        gL[nl][((g^(nl&7))<<3) + (c&7)] = gv;
      }
    }
  }
  __syncthreads();   // gL ready; tiles 16,17,18 landed (full vmcnt drain)

  // ---- phase 3: ff2 GEMM (16 x 256, K=1024), pipelined w2 ----
  {
    f4v e0={0,0,0,0}, e1={0,0,0,0};
    int c0i = wv*16 + lo;
    int c1i = c0i + 128;
    for (int kt=0; kt<16; ++kt){
      int g = 16 + kt;                         // global tile 16..31
      const unsigned char* bufp = wS[g%3];
      #pragma unroll
      for (int ks=0; ks<2; ++ks){
        int k0 = kt*64 + ks*32;
        s8v a = *(const s8v*)&gL[lo][(((hi + (k0>>3)) ^ (lo&7))<<3)];
        s8v bw0 = *(const s8v*)(bufp + c0i*128 + ((((ks*4)+hi) ^ (c0i&7))<<4));
        s8v bw1 = *(const s8v*)(bufp + c1i*128 + ((((ks*4)+hi) ^ (c1i&7))<<4));
        e0 = __builtin_amdgcn_mfma_f32_16x16x32_bf16(a, bw0, e0,0,0,0);
        e1 = __builtin_amdgcn_mfma_f32_16x16x32_bf16(a, bw1, e1,0,0,0);
      }
      asm volatile("" ::: "memory");
      __builtin_amdgcn_s_barrier();            // all waves done reading wS[g%3]
      if (g+3 <= 31) { STAGE_G(g+3); }
      if (g <= 28){
        asm volatile("s_waitcnt vmcnt(8)" ::: "memory");  // tile g+1 landed
        __builtin_amdgcn_s_barrier();
      } else if (g == 29){
        asm volatile("s_waitcnt vmcnt(4)" ::: "memory");  // tile 30 landed
        __builtin_amdgcn_s_barrier();
      } else if (g == 30){
        asm volatile("s_waitcnt vmcnt(0)" ::: "memory");  // tile 31 landed
        __builtin_amdgcn_s_barrier();
      }
    }
    #pragma unroll
    for (int jj=0;jj<2;jj++){
      f4v acc = jj? e1 : e0;
      int c = jj*128 + wv*16 + lo;
      float bc = b2r[jj];
      #pragma unroll
      for (int r=0;r<4;r++){
        int n = r0 + hi*4 + r;
        outp[n*DM+c] = acc[r] + bc + t[jj][r];   // residual from registers
      }
    }
  }
#undef STAGE_G
#undef STAGE_W1
#undef STAGE_W2
}

extern "C" void kernel_launch(void* const* d_in, const int* in_sizes, int n_in,
                              void* d_out, int out_size, void* d_ws, size_t ws_size,
                              hipStream_t stream){
  const float* x     = (const float*)d_in[0];
  const int*   adj   = (const int*)d_in[1];
  const float* wqkv  = (const float*)d_in[2];
  const float* wproj = (const float*)d_in[3];
  const float* bproj = (const float*)d_in[4];
  const float* w1    = (const float*)d_in[5];
  const float* b1    = (const float*)d_in[6];
  const float* w2    = (const float*)d_in[7];
  const float* b2    = (const float*)d_in[8];
  const float* g1    = (const float*)d_in[9];
  const float* be1   = (const float*)d_in[10];
  const float* g2    = (const float*)d_in[11];
  const float* be2   = (const float*)d_in[12];

  char* ws = (char*)d_ws;
  unsigned short* h1    = (unsigned short*)(ws + (0u<<20));
  unsigned short* Qb    = (unsigned short*)(ws + (2u<<20));
  unsigned short* Kb    = (unsigned short*)(ws + (4u<<20));
  unsigned short* Vt    = (unsigned short*)(ws + (6u<<20));
  unsigned short* ao    = (unsigned short*)(ws + (8u<<20));
  unsigned short* wqkvT = (unsigned short*)(ws + (24u<<20));
  unsigned short* wprojT= (unsigned short*)(ws + (25u<<20));
  unsigned short* w1T   = (unsigned short*)(ws + (26u<<20));
  unsigned short* w2T   = (unsigned short*)(ws + (27u<<20));
  unsigned long long* mbits = (unsigned long long*)(ws + (28u<<20));
  float* outF = (float*)d_out;

  hipLaunchKernelGGL(prologue_kernel, dim3(256), dim3(256), 0, stream,
                     wqkv, wproj, w1, w2, wqkvT, wprojT, w1T, w2T,
                     x, g1, be1, h1);
  hipLaunchKernelGGL((gemm24<256,0>), dim3(11,128), dim3(256), 0, stream,
                     h1, wqkvT, adj, mbits, Qb, Kb, Vt);
  hipLaunchKernelGGL(attn_kernel, dim3(8,64), dim3(512), 0, stream,
                     Qb, Kb, Vt, (const unsigned*)mbits, ao);
  hipLaunchKernelGGL(tail_kernel, dim3(256), dim3(512), 0, stream,
                     ao, wprojT, bproj, x, g2, be2, w1T, b1, w2T, b2, outF);
}

// Round 19
// 95.317 us; speedup vs baseline: 1.0326x; 1.0308x over previous
//
#include <hip/hip_runtime.h>
#include <hip/hip_bf16.h>

#define NT 4096
#define DM 256
#define NH 8
#define HD 32
#define DFF 1024

typedef __attribute__((ext_vector_type(8))) short s8v;
typedef __attribute__((ext_vector_type(4))) float f4v;
typedef __attribute__((ext_vector_type(2))) float f2v;
typedef __attribute__((ext_vector_type(16))) float f16v;
typedef __attribute__((ext_vector_type(4))) int i4v;

static __device__ __forceinline__ unsigned short f2b(float f){
  union{float f; unsigned u;} v; v.f=f;
  return (unsigned short)((v.u + 0x7FFFu + ((v.u>>16)&1u))>>16);
}

// async global->LDS DMA, 16B per lane (emits global_load_lds_dwordx4).
static __device__ __forceinline__ void gl_lds16(const void* g, void* l){
  __builtin_amdgcn_global_load_lds(
      (const __attribute__((address_space(1))) unsigned int*)g,
      (__attribute__((address_space(3))) unsigned int*)l, 16, 0, 0);
}

// ---- prologue: prep_weights (blocks 0..127) | ln1 (128..255) ----
__global__ __launch_bounds__(256) void prologue_kernel(
    const float* __restrict__ wqkv, const float* __restrict__ wproj,
    const float* __restrict__ w1, const float* __restrict__ w2,
    unsigned short* __restrict__ wqkvT, unsigned short* __restrict__ wprojT,
    unsigned short* __restrict__ w1T, unsigned short* __restrict__ w2T,
    const float* __restrict__ x, const float* __restrict__ g1,
    const float* __restrict__ be1, unsigned short* __restrict__ h1){
  int bx = blockIdx.x;
  if (bx < 128){
    int t = bx*256 + threadIdx.x;
    const int stride = 128*256;
    for (int i=t;i<768*DM;i+=stride){int n=i>>8,k=i&255; wqkvT[i]=f2b(wqkv[k*768+n]);}
    for (int i=t;i<DM*DM;i+=stride){int n=i>>8,k=i&255; wprojT[i]=f2b(wproj[k*DM+n]);}
    for (int i=t;i<DFF*DM;i+=stride){int n=i>>8,k=i&255; w1T[i]=f2b(w1[k*DFF+n]);}
    for (int i=t;i<DM*DFF;i+=stride){int n=i/DFF,k=i-n*DFF; w2T[i]=f2b(w2[k*DM+n]);}
  } else {
    int wv = threadIdx.x>>6, lane = threadIdx.x&63;
    int rbase = (bx-128)*4 + wv;        // 512 row-streams, 8 rows each
    for (int j=0;j<8;j++){
      int row = rbase + j*512;
      float4 v = *(const float4*)(x + row*DM + lane*4);
      float s = v.x+v.y+v.z+v.w;
      float sq = v.x*v.x+v.y*v.y+v.z*v.z+v.w*v.w;
      #pragma unroll
      for (int m=1;m<64;m<<=1){ s += __shfl_xor(s,m); sq += __shfl_xor(sq,m); }
      float mu = s*(1.0f/DM);
      float rs = rsqrtf(sq*(1.0f/DM) - mu*mu + 1e-5f);
      float4 gv = *(const float4*)(g1 + lane*4);
      float4 bv = *(const float4*)(be1 + lane*4);
      ushort4 o;
      o.x = f2b((v.x-mu)*rs*gv.x + bv.x);
      o.y = f2b((v.y-mu)*rs*gv.y + bv.y);
      o.z = f2b((v.z-mu)*rs*gv.z + bv.z);
      o.w = f2b((v.w-mu)*rs*gv.w + bv.w);
      *(ushort4*)(h1 + row*DM + lane*4) = o;
    }
  }
}

// ---- qkv GEMM + pack_adj co-scheduled: grid (11,128) ----
// K and V are now written in FRAGMENT layout (per head, per 32-key tile):
//   2KB/tile = [frag0: 64 lanes x 16B][frag1: 64 lanes x 16B], where byte
//   addr tile*2048 + frag*1024 + lane*16 holds exactly the 16B that attn
//   lane (l31=lane&31, hi5=lane>>5) consumes. attn K/V loads become fully
//   coalesced 1KB wave-loads (16 lines, 100% util) instead of 64-line
//   gathers (TA-throughput relief). Per-lane register contents unchanged.
//   K element (key n, d): frag=d>>4, lane=((d>>3)&1)*32 + (n&31), el=d&7.
//   V element (key n, d): kk=n&31; frag=kk>>4, lane=((kk>>3)&1)*32 + d, el=kk&7.
template<int KD, int MODE>
__global__ __launch_bounds__(256,4) void gemm24(const unsigned short* __restrict__ A,
            const unsigned short* __restrict__ Wt,
            const int* __restrict__ adj, unsigned long long* __restrict__ mask,
            unsigned short* __restrict__ Qp, unsigned short* __restrict__ Kp,
            unsigned short* __restrict__ Vt){
  int wv = threadIdx.x>>6, lane = threadIdx.x&63;
  if (blockIdx.x >= 3){
    int bxl = (blockIdx.x-3)*128 + blockIdx.y;   // 0..1023
    int base = (bxl*4 + wv)*64;                  // 64 mask words per wave
    for (int it=0; it<16; ++it){
      int w0 = base + it*4;
      unsigned long long b0 = __ballot(adj[(long)(w0+0)*64 + lane]!=0);
      unsigned long long b1 = __ballot(adj[(long)(w0+1)*64 + lane]!=0);
      unsigned long long b2 = __ballot(adj[(long)(w0+2)*64 + lane]!=0);
      unsigned long long b3 = __ballot(adj[(long)(w0+3)*64 + lane]!=0);
      if (lane==0){ mask[w0]=b0; mask[w0+1]=b1; mask[w0+2]=b2; mask[w0+3]=b3; }
    }
    return;
  }
  int lo = lane&15, hi = lane>>4;
  int r0 = blockIdx.y*32;
  int cbase = blockIdx.x*256 + wv*16;
  const unsigned short* ar0 = A + (r0+lo)*KD + hi*8;
  const unsigned short* ar1 = ar0 + 16*KD;
  const unsigned short* br0 = Wt + (cbase     +lo)*KD + hi*8;
  const unsigned short* br1 = Wt + (cbase+ 64 +lo)*KD + hi*8;
  const unsigned short* br2 = Wt + (cbase+128 +lo)*KD + hi*8;
  const unsigned short* br3 = Wt + (cbase+192 +lo)*KD + hi*8;
  f4v c00={0,0,0,0},c01={0,0,0,0},c02={0,0,0,0},c03={0,0,0,0};
  f4v c10={0,0,0,0},c11={0,0,0,0},c12={0,0,0,0},c13={0,0,0,0};
  #pragma unroll 2
  for (int k0=0;k0<KD;k0+=32){
    s8v a0 = *(const s8v*)(ar0 + k0);
    s8v a1 = *(const s8v*)(ar1 + k0);
    s8v b0 = *(const s8v*)(br0 + k0);
    s8v b1 = *(const s8v*)(br1 + k0);
    s8v b2 = *(const s8v*)(br2 + k0);
    s8v b3 = *(const s8v*)(br3 + k0);
    c00 = __builtin_amdgcn_mfma_f32_16x16x32_bf16(a0,b0,c00,0,0,0);
    c10 = __builtin_amdgcn_mfma_f32_16x16x32_bf16(a1,b0,c10,0,0,0);
    c01 = __builtin_amdgcn_mfma_f32_16x16x32_bf16(a0,b1,c01,0,0,0);
    c11 = __builtin_amdgcn_mfma_f32_16x16x32_bf16(a1,b1,c11,0,0,0);
    c02 = __builtin_amdgcn_mfma_f32_16x16x32_bf16(a0,b2,c02,0,0,0);
    c12 = __builtin_amdgcn_mfma_f32_16x16x32_bf16(a1,b2,c12,0,0,0);
    c03 = __builtin_amdgcn_mfma_f32_16x16x32_bf16(a0,b3,c03,0,0,0);
    c13 = __builtin_amdgcn_mfma_f32_16x16x32_bf16(a1,b3,c13,0,0,0);
  }
  const float scl2 = (float)(0.17677669529663687 * 1.4426950408889634); // scl*log2e
  #pragma unroll
  for (int rt=0;rt<2;rt++){
    f4v e0 = rt? c10:c00, e1 = rt? c11:c01, e2 = rt? c12:c02, e3 = rt? c13:c03;
    int nb = r0 + rt*16 + hi*4;
    #pragma unroll
    for (int jj=0;jj<4;jj++){
      f4v acc = jj==0?e0 : jj==1?e1 : jj==2?e2 : e3;
      int c = cbase + jj*64 + lo;
      int which = c>>8, hd = c&255, hh = hd>>5, d = hd&31;
      #pragma unroll
      for (int r=0;r<4;r++){
        int n = nb + r;
        float val = acc[r];
        if (which==0){
          Qp[(hh*NT+n)*HD+d] = f2b(val*scl2);
        } else if (which==1){
          int idx = (n>>5)*1024 + (d>>4)*512 + ((((d>>3)&1)<<5) + (n&31))*8 + (d&7);
          Kp[hh*(NT*HD) + idx] = f2b(val);
        } else {
          int kk = n&31;
          int idx = (n>>5)*1024 + (kk>>4)*512 + ((((kk>>3)&1)<<5) + d)*8 + (kk&7);
          Vt[hh*(NT*HD) + idx] = f2b(val);
        }
      }
    }
  }
}

// ---- flash attention (r9 structure + fragment-layout coalesced K/V) ----
// K/V loads are now 1KB contiguous wave-loads: addr = base + tile*2048 +
// frag*1024 + lane*16 (see gemm24 layout comment). Register contents per
// lane are identical to the old strided loads -> MFMA semantics unchanged.
__global__ __launch_bounds__(512,2) void attn_kernel(
    const unsigned short* __restrict__ Q, const unsigned short* __restrict__ K,
    const unsigned short* __restrict__ Vt, const unsigned* __restrict__ mb32,
    unsigned short* __restrict__ out){
  __shared__ float Opart[8][32][34];
  __shared__ float llS[8][32];
  int wv = threadIdx.x>>6, lane = threadIdx.x&63;
  int l31 = lane&31, hi5 = lane>>5;
  int h = blockIdx.x, q0 = blockIdx.y*64;
  const unsigned short* QbA = Q + (h*NT + q0 + l31)*HD + hi5*8;
  const unsigned short* QbB = QbA + 32*HD;
  s8v bqA1 = *(const s8v*)(QbA);
  s8v bqA2 = *(const s8v*)(QbA + 16);
  s8v bqB1 = *(const s8v*)(QbB);
  s8v bqB2 = *(const s8v*)(QbB + 16);
  const unsigned short* Kb = K  + h*(NT*HD) + lane*8;   // fragment layout
  const unsigned short* Vb = Vt + h*(NT*HD) + lane*8;   // fragment layout
  const unsigned* mrowA = mb32 + (q0+l31)*(NT/32) + wv*16;
  const unsigned* mrowB = mrowA + 32*(NT/32);
  const float C0 = -11.541560327111707f;   // -8*log2e
  const f16v c0v = {C0,C0,C0,C0,C0,C0,C0,C0,C0,C0,C0,C0,C0,C0,C0,C0};
  f2v lacA = {0.f,0.f}, lacB = {0.f,0.f};
  f16v accA = {0,0,0,0,0,0,0,0,0,0,0,0,0,0,0,0};
  f16v accB = {0,0,0,0,0,0,0,0,0,0,0,0,0,0,0,0};
  union SU { f16v v; f2v p[8]; };
  // initial K tile (tile index wv*16), coalesced 1KB loads
  s8v kc1 = *(const s8v*)(Kb + (wv*16)*1024);
  s8v kc2 = *(const s8v*)(Kb + (wv*16)*1024 + 512);
  for (int tg=0; tg<4; tg++){
    i4v mw4A = *(const i4v*)(mrowA + tg*4);
    i4v mw4B = *(const i4v*)(mrowB + tg*4);
    #pragma unroll
    for (int ti=0; ti<4; ti++){
      int t = tg*4 + ti;
      int tl = wv*16 + t;
      // V for current tile: coalesced fragment loads, issue early
      s8v av1 = *(const s8v*)(Vb + tl*1024);
      s8v av2 = *(const s8v*)(Vb + tl*1024 + 512);
      // prefetch next K tile while this tile's VALU runs
      int tn = (t<15)? t+1 : 15;
      const unsigned short* Ktn = Kb + (wv*16 + tn)*1024;
      s8v kn1 = *(const s8v*)(Ktn);
      s8v kn2 = *(const s8v*)(Ktn + 512);
      SU sa, sb;
      __builtin_amdgcn_s_setprio(1);
      sa.v = __builtin_amdgcn_mfma_f32_32x32x16_bf16(kc1, bqA1, c0v, 0,0,0);
      sa.v = __builtin_amdgcn_mfma_f32_32x32x16_bf16(kc2, bqA2, sa.v, 0,0,0);
      sb.v = __builtin_amdgcn_mfma_f32_32x32x16_bf16(kc1, bqB1, c0v, 0,0,0);
      sb.v = __builtin_amdgcn_mfma_f32_32x32x16_bf16(kc2, bqB2, sb.v, 0,0,0);
      __builtin_amdgcn_s_setprio(0);
      unsigned mwA = ((unsigned)mw4A[ti]) >> (4*hi5);
      unsigned mwB = ((unsigned)mw4B[ti]) >> (4*hi5);
      #pragma unroll
      for (int r=0;r<16;r++){
        int bp = (r&3)+8*(r>>2);
        float pa = __builtin_amdgcn_exp2f(sa.v[r]);
        float pb = __builtin_amdgcn_exp2f(sb.v[r]);
        sa.v[r] = ((mwA >> bp) & 1u) ? pa : 0.0f;
        sb.v[r] = ((mwB >> bp) & 1u) ? pb : 0.0f;
      }
      #pragma unroll
      for (int i=0;i<8;i++){ lacA += sa.p[i]; lacB += sb.p[i]; }
      unsigned a0,a1,a2,a3,a4,a5,a6,a7, b0,b1,b2,b3,b4,b5,b6,b7;
      asm("v_cvt_pk_bf16_f32 %0, %1, %2" : "=v"(a0) : "v"(sa.v[0]),  "v"(sa.v[1]));
      asm("v_cvt_pk_bf16_f32 %0, %1, %2" : "=v"(a1) : "v"(sa.v[2]),  "v"(sa.v[3]));
      asm("v_cvt_pk_bf16_f32 %0, %1, %2" : "=v"(a2) : "v"(sa.v[4]),  "v"(sa.v[5]));
      asm("v_cvt_pk_bf16_f32 %0, %1, %2" : "=v"(a3) : "v"(sa.v[6]),  "v"(sa.v[7]));
      asm("v_cvt_pk_bf16_f32 %0, %1, %2" : "=v"(a4) : "v"(sa.v[8]),  "v"(sa.v[9]));
      asm("v_cvt_pk_bf16_f32 %0, %1, %2" : "=v"(a5) : "v"(sa.v[10]), "v"(sa.v[11]));
      asm("v_cvt_pk_bf16_f32 %0, %1, %2" : "=v"(a6) : "v"(sa.v[12]), "v"(sa.v[13]));
      asm("v_cvt_pk_bf16_f32 %0, %1, %2" : "=v"(a7) : "v"(sa.v[14]), "v"(sa.v[15]));
      asm("v_permlane32_swap_b32 %0, %1" : "+v"(a0), "+v"(a2));
      asm("v_permlane32_swap_b32 %0, %1" : "+v"(a1), "+v"(a3));
      asm("v_permlane32_swap_b32 %0, %1" : "+v"(a4), "+v"(a6));
      asm("v_permlane32_swap_b32 %0, %1" : "+v"(a5), "+v"(a7));
      asm("v_cvt_pk_bf16_f32 %0, %1, %2" : "=v"(b0) : "v"(sb.v[0]),  "v"(sb.v[1]));
      asm("v_cvt_pk_bf16_f32 %0, %1, %2" : "=v"(b1) : "v"(sb.v[2]),  "v"(sb.v[3]));
      asm("v_cvt_pk_bf16_f32 %0, %1, %2" : "=v"(b2) : "v"(sb.v[4]),  "v"(sb.v[5]));
      asm("v_cvt_pk_bf16_f32 %0, %1, %2" : "=v"(b3) : "v"(sb.v[6]),  "v"(sb.v[7]));
      asm("v_cvt_pk_bf16_f32 %0, %1, %2" : "=v"(b4) : "v"(sb.v[8]),  "v"(sb.v[9]));
      asm("v_cvt_pk_bf16_f32 %0, %1, %2" : "=v"(b5) : "v"(sb.v[10]), "v"(sb.v[11]));
      asm("v_cvt_pk_bf16_f32 %0, %1, %2" : "=v"(b6) : "v"(sb.v[12]), "v"(sb.v[13]));
      asm("v_cvt_pk_bf16_f32 %0, %1, %2" : "=v"(b7) : "v"(sb.v[14]), "v"(sb.v[15]));
      asm("v_permlane32_swap_b32 %0, %1" : "+v"(b0), "+v"(b2));
      asm("v_permlane32_swap_b32 %0, %1" : "+v"(b1), "+v"(b3));
      asm("v_permlane32_swap_b32 %0, %1" : "+v"(b4), "+v"(b6));
      asm("v_permlane32_swap_b32 %0, %1" : "+v"(b5), "+v"(b7));
      i4v pA1i = {(int)a0,(int)a1,(int)a2,(int)a3};
      i4v pA2i = {(int)a4,(int)a5,(int)a6,(int)a7};
      i4v pB1i = {(int)b0,(int)b1,(int)b2,(int)b3};
      i4v pB2i = {(int)b4,(int)b5,(int)b6,(int)b7};
      s8v pA1 = __builtin_bit_cast(s8v, pA1i);
      s8v pA2 = __builtin_bit_cast(s8v, pA2i);
      s8v pB1 = __builtin_bit_cast(s8v, pB1i);
      s8v pB2 = __builtin_bit_cast(s8v, pB2i);
      __builtin_amdgcn_s_setprio(1);
      accA = __builtin_amdgcn_mfma_f32_32x32x16_bf16(av1, pA1, accA, 0,0,0);
      accA = __builtin_amdgcn_mfma_f32_32x32x16_bf16(av2, pA2, accA, 0,0,0);
      accB = __builtin_amdgcn_mfma_f32_32x32x16_bf16(av1, pB1, accB, 0,0,0);
      accB = __builtin_amdgcn_mfma_f32_32x32x16_bf16(av2, pB2, accB, 0,0,0);
      __builtin_amdgcn_s_setprio(0);
      kc1 = kn1; kc2 = kn2;
    }
  }
  int tid = threadIdx.x;
  int qq = tid>>4, dd = 2*(tid&15);
  // ---- pass A ----
  #pragma unroll
  for (int i=0;i<8;i++){
    int d = (2*i&3) + 8*(i>>1) + 4*hi5;
    float2 p2; p2.x = accA[2*i]; p2.y = accA[2*i+1];
    *(float2*)&Opart[wv][l31][d] = p2;
  }
  float lsumA = lacA[0] + lacA[1];
  lsumA += __shfl_xor(lsumA, 32);
  if (hi5==0) llS[wv][l31] = lsumA;
  __syncthreads();
  {
    float L=0.f, o0=0.f, o1=0.f;
    #pragma unroll
    for (int u=0;u<8;u++){
      L  += llS[u][qq];
      o0 += Opart[u][qq][dd];
      o1 += Opart[u][qq][dd+1];
    }
    float inv = 1.0f/L;
    float r0 = o0*inv, r1 = o1*inv;
    unsigned pw;
    asm("v_cvt_pk_bf16_f32 %0, %1, %2" : "=v"(pw) : "v"(r0), "v"(r1));
    *(unsigned*)(out + (q0+qq)*DM + h*HD + dd) = pw;
  }
  __syncthreads();
  // ---- pass B ----
  #pragma unroll
  for (int i=0;i<8;i++){
    int d = (2*i&3) + 8*(i>>1) + 4*hi5;
    float2 p2; p2.x = accB[2*i]; p2.y = accB[2*i+1];
    *(float2*)&Opart[wv][l31][d] = p2;
  }
  float lsumB = lacB[0] + lacB[1];
  lsumB += __shfl_xor(lsumB, 32);
  if (hi5==0) llS[wv][l31] = lsumB;
  __syncthreads();
  {
    float L=0.f, o0=0.f, o1=0.f;
    #pragma unroll
    for (int u=0;u<8;u++){
      L  += llS[u][qq];
      o0 += Opart[u][qq][dd];
      o1 += Opart[u][qq][dd+1];
    }
    float inv = 1.0f/L;
    float r0 = o0*inv, r1 = o1*inv;
    unsigned pw;
    asm("v_cvt_pk_bf16_f32 %0, %1, %2" : "=v"(pw) : "v"(r0), "v"(r1));
    *(unsigned*)(out + (q0+32+qq)*DM + h*HD + dd) = pw;
  }
}

// ---- fused tail (depth-3 counted-vmcnt staging pipeline; best measured) ----
__global__ __launch_bounds__(512,2) void tail_kernel(
    const unsigned short* __restrict__ ao, const unsigned short* __restrict__ wprojT,
    const float* __restrict__ bproj, const float* __restrict__ x,
    const float* __restrict__ g2, const float* __restrict__ be2,
    const unsigned short* __restrict__ w1T, const float* __restrict__ b1,
    const unsigned short* __restrict__ w2T, const float* __restrict__ b2,
    float* __restrict__ outp){
  __shared__ unsigned short h2L[16][DM];
  __shared__ unsigned short gL[16][DFF];
  __shared__ float Ss[8][16], Sq[8][16];
  __shared__ __align__(16) unsigned char wS[3][32768];
  int wv = threadIdx.x>>6, lane = threadIdx.x&63;
  int lo = lane&15, hi = lane>>4;
  int tid = threadIdx.x;
  int r0 = blockIdx.x*16;
  float t[2][4];                      // x2 residual, live across all phases

#define STAGE_W1(S_, BUF_)                                                    \
  do { int cb_ = (S_)>>2, kt_ = (S_)&3;                                       \
    _Pragma("unroll")                                                         \
    for (int rr=0; rr<4; ++rr){                                               \
      int col_ = cb_*256 + rr*64 + (tid>>3);                                  \
      int ko_  = (tid&7) ^ (col_&7);                                          \
      gl_lds16(w1T + col_*DM + kt_*64 + ko_*8,                                \
               &wS[BUF_][rr*8192 + tid*16]);                                  \
    } } while(0)

#define STAGE_W2(KT, BUF)                                                     \
  do { _Pragma("unroll")                                                      \
    for (int rr=0; rr<4; ++rr){                                               \
      int col_ = rr*64 + (tid>>3);                                            \
      int ko_  = (tid&7) ^ (col_&7);                                          \
      gl_lds16(w2T + col_*DFF + (KT)*64 + ko_*8,                              \
               &wS[BUF][rr*8192 + tid*16]);                                   \
    } } while(0)

#define STAGE_G(G_)                                                           \
  do { int gg_ = (G_);                                                        \
    if (gg_ < 16) { STAGE_W1(gg_, gg_%3); }                                   \
    else          { STAGE_W2(gg_-16, gg_%3); }                                \
  } while(0)

  // pre-issue tiles 0,1,2: they stream during the whole of phase 1.
  STAGE_G(0);
  STAGE_G(1);
  STAGE_G(2);

  // preload bias scalars so the pipelined loops contain NO VMEM
  // other than the staging DMAs (keeps vmcnt accounting exact).
  float b1r[4][2], b2r[2];
  #pragma unroll
  for (int cb=0; cb<4; ++cb){
    b1r[cb][0] = b1[cb*256 +        wv*16 + lo];
    b1r[cb][1] = b1[cb*256 + 128 +  wv*16 + lo];
  }
  b2r[0] = b2[       wv*16 + lo];
  b2r[1] = b2[128 +  wv*16 + lo];

  // ---- phase 1: proj GEMM (16 rows x 256 cols, K=256) + residual + LN ----
  {
    const unsigned short* ar  = ao + (r0+lo)*DM + hi*8;
    const unsigned short* pb0 = wprojT + (wv*16     +lo)*DM + hi*8;
    const unsigned short* pb1 = wprojT + (wv*16+128 +lo)*DM + hi*8;
    f4v a0={0,0,0,0}, a1={0,0,0,0};
    #pragma unroll
    for (int k0=0;k0<DM;k0+=32){
      s8v a = *(const s8v*)(ar + k0);
      a0 = __builtin_amdgcn_mfma_f32_16x16x32_bf16(a, *(const s8v*)(pb0+k0), a0,0,0,0);
      a1 = __builtin_amdgcn_mfma_f32_16x16x32_bf16(a, *(const s8v*)(pb1+k0), a1,0,0,0);
    }
    float sr[4]={0,0,0,0}, sq[4]={0,0,0,0};
    #pragma unroll
    for (int jj=0;jj<2;jj++){
      f4v acc = jj? a1 : a0;
      int c = jj*128 + wv*16 + lo;
      float bc = bproj[c];
      #pragma unroll
      for (int r=0;r<4;r++){
        int n = r0 + hi*4 + r;
        float tv = acc[r] + bc + x[n*DM+c];
        t[jj][r] = tv; sr[r] += tv; sq[r] += tv*tv;
      }
    }
    #pragma unroll
    for (int m=1;m<16;m<<=1){
      #pragma unroll
      for (int r=0;r<4;r++){ sr[r]+=__shfl_xor(sr[r],m); sq[r]+=__shfl_xor(sq[r],m); }
    }
    if (lo==0){
      #pragma unroll
      for (int r=0;r<4;r++){ Ss[wv][hi*4+r]=sr[r]; Sq[wv][hi*4+r]=sq[r]; }
    }
    __syncthreads();
    #pragma unroll
    for (int r=0;r<4;r++){
      int nl = hi*4+r;
      float S=0.f, Qs=0.f;
      #pragma unroll
      for (int u=0;u<8;u++){ S += Ss[u][nl]; Qs += Sq[u][nl]; }
      float mu = S*(1.0f/DM);
      float rs = rsqrtf(Qs*(1.0f/DM) - mu*mu + 1e-5f);
      #pragma unroll
      for (int jj=0;jj<2;jj++){
        int c = jj*128 + wv*16 + lo;
        unsigned short hv = f2b((t[jj][r]-mu)*rs*g2[c] + be2[c]);
        int g = c>>3;
        h2L[nl][((g^(nl&7))<<3) + (c&7)] = hv;
      }
    }
  }
  __syncthreads();   // h2L ready; tiles 0,1,2 landed (full vmcnt drain)

  // ---- phase 2: ff1 GEMM (16 x 1024, K=256) + gelu -> gL, pipelined ----
  for (int cb=0; cb<4; ++cb){
    f4v f0={0,0,0,0}, f1={0,0,0,0};
    int c0i = wv*16 + lo;
    int c1i = c0i + 128;
    #pragma unroll
    for (int kt=0; kt<4; ++kt){
      int g = cb*4 + kt;                       // global tile 0..15
      const unsigned char* bufp = wS[g%3];
      #pragma unroll
      for (int ks=0; ks<2; ++ks){
        int k0 = kt*64 + ks*32;
        s8v a  = *(const s8v*)&h2L[lo][(((hi + (k0>>3)) ^ (lo&7))<<3)];
        s8v bw0 = *(const s8v*)(bufp + c0i*128 + ((((ks*4)+hi) ^ (c0i&7))<<4));
        s8v bw1 = *(const s8v*)(bufp + c1i*128 + ((((ks*4)+hi) ^ (c1i&7))<<4));
        f0 = __builtin_amdgcn_mfma_f32_16x16x32_bf16(a, bw0, f0,0,0,0);
        f1 = __builtin_amdgcn_mfma_f32_16x16x32_bf16(a, bw1, f1,0,0,0);
      }
      asm volatile("" ::: "memory");
      __builtin_amdgcn_s_barrier();            // all waves done reading wS[g%3]
      STAGE_G(g+3);                            // g+3 <= 18 here
      if (g < 15){
        asm volatile("s_waitcnt vmcnt(8)" ::: "memory");  // tile g+1 landed
        __builtin_amdgcn_s_barrier();                     // ...for all waves
      }
    }
    // gelu epilogue for this col-block (no VMEM: bias preloaded)
    #pragma unroll
    for (int jj=0;jj<2;jj++){
      f4v acc = jj? f1 : f0;
      int c = cb*256 + jj*128 + wv*16 + lo;
      float bc = b1r[cb][jj];
      #pragma unroll
      for (int r=0;r<4;r++){
        int nl = hi*4+r;
        float xx = acc[r] + bc;
        float x2v = xx*xx;
        float arg = xx*(2.302340531f + 0.102952640f*x2v);
        float e  = __builtin_amdgcn_exp2f(arg);
        float rcp = __builtin_amdgcn_rcpf(e + 1.0f);
        unsigned short gv = f2b(xx - xx*rcp);
        int g = c>>3;
        gL[nl][((g^(nl&7))<<3) + (c&7)] = gv;
      }
    }
  }
  __syncthreads();   // gL ready; tiles 16,17,18 landed (full vmcnt drain)

  // ---- phase 3: ff2 GEMM (16 x 256, K=1024), pipelined w2 ----
  {
    f4v e0={0,0,0,0}, e1={0,0,0,0};
    int c0i = wv*16 + lo;
    int c1i = c0i + 128;
    for (int kt=0; kt<16; ++kt){
      int g = 16 + kt;                         // global tile 16..31
      const unsigned char* bufp = wS[g%3];
      #pragma unroll
      for (int ks=0; ks<2; ++ks){
        int k0 = kt*64 + ks*32;
        s8v a = *(const s8v*)&gL[lo][(((hi + (k0>>3)) ^ (lo&7))<<3)];
        s8v bw0 = *(const s8v*)(bufp + c0i*128 + ((((ks*4)+hi) ^ (c0i&7))<<4));
        s8v bw1 = *(const s8v*)(bufp + c1i*128 + ((((ks*4)+hi) ^ (c1i&7))<<4));
        e0 = __builtin_amdgcn_mfma_f32_16x16x32_bf16(a, bw0, e0,0,0,0);
        e1 = __builtin_amdgcn_mfma_f32_16x16x32_bf16(a, bw1, e1,0,0,0);
      }
      asm volatile("" ::: "memory");
      __builtin_amdgcn_s_barrier();            // all waves done reading wS[g%3]
      if (g+3 <= 31) { STAGE_G(g+3); }
      if (g <= 28){
        asm volatile("s_waitcnt vmcnt(8)" ::: "memory");  // tile g+1 landed
        __builtin_amdgcn_s_barrier();
      } else if (g == 29){
        asm volatile("s_waitcnt vmcnt(4)" ::: "memory");  // tile 30 landed
        __builtin_amdgcn_s_barrier();
      } else if (g == 30){
        asm volatile("s_waitcnt vmcnt(0)" ::: "memory");  // tile 31 landed
        __builtin_amdgcn_s_barrier();
      }
    }
    #pragma unroll
    for (int jj=0;jj<2;jj++){
      f4v acc = jj? e1 : e0;
      int c = jj*128 + wv*16 + lo;
      float bc = b2r[jj];
      #pragma unroll
      for (int r=0;r<4;r++){
        int n = r0 + hi*4 + r;
        outp[n*DM+c] = acc[r] + bc + t[jj][r];   // residual from registers
      }
    }
  }
#undef STAGE_G
#undef STAGE_W1
#undef STAGE_W2
}

extern "C" void kernel_launch(void* const* d_in, const int* in_sizes, int n_in,
                              void* d_out, int out_size, void* d_ws, size_t ws_size,
                              hipStream_t stream){
  const float* x     = (const float*)d_in[0];
  const int*   adj   = (const int*)d_in[1];
  const float* wqkv  = (const float*)d_in[2];
  const float* wproj = (const float*)d_in[3];
  const float* bproj = (const float*)d_in[4];
  const float* w1    = (const float*)d_in[5];
  const float* b1    = (const float*)d_in[6];
  const float* w2    = (const float*)d_in[7];
  const float* b2    = (const float*)d_in[8];
  const float* g1    = (const float*)d_in[9];
  const float* be1   = (const float*)d_in[10];
  const float* g2    = (const float*)d_in[11];
  const float* be2   = (const float*)d_in[12];

  char* ws = (char*)d_ws;
  unsigned short* h1    = (unsigned short*)(ws + (0u<<20));
  unsigned short* Qb    = (unsigned short*)(ws + (2u<<20));
  unsigned short* Kb    = (unsigned short*)(ws + (4u<<20));
  unsigned short* Vt    = (unsigned short*)(ws + (6u<<20));
  unsigned short* ao    = (unsigned short*)(ws + (8u<<20));
  unsigned short* wqkvT = (unsigned short*)(ws + (24u<<20));
  unsigned short* wprojT= (unsigned short*)(ws + (25u<<20));
  unsigned short* w1T   = (unsigned short*)(ws + (26u<<20));
  unsigned short* w2T   = (unsigned short*)(ws + (27u<<20));
  unsigned long long* mbits = (unsigned long long*)(ws + (28u<<20));
  float* outF = (float*)d_out;

  hipLaunchKernelGGL(prologue_kernel, dim3(256), dim3(256), 0, stream,
                     wqkv, wproj, w1, w2, wqkvT, wprojT, w1T, w2T,
                     x, g1, be1, h1);
  hipLaunchKernelGGL((gemm24<256,0>), dim3(11,128), dim3(256), 0, stream,
                     h1, wqkvT, adj, mbits, Qb, Kb, Vt);
  hipLaunchKernelGGL(attn_kernel, dim3(8,64), dim3(512), 0, stream,
                     Qb, Kb, Vt, (const unsigned*)mbits, ao);
  hipLaunchKernelGGL(tail_kernel, dim3(256), dim3(512), 0, stream,
                     ao, wprojT, bproj, x, g2, be2, w1T, b1, w2T, b2, outF);
}